// Round 7
// baseline (9527.171 us; speedup 1.0000x reference)
//
#include <hip/hip_runtime.h>
#include <math.h>

#define BB 128
#define TT 512
#define FF 128
#define HH 512
#define NR 2048      // gate rows, row = 4*j + g
#define HB (HH*BB)   // 65536 words per h state
#define FLS 16       // flag stride (ints): one flag per 64B line

typedef __attribute__((ext_vector_type(8))) short short8;   // 8 bf16
typedef __attribute__((ext_vector_type(4))) float f32x4;    // MFMA C/D frag
typedef unsigned int uint;
typedef unsigned short ushort;
typedef unsigned long long u64;

#define MFMA __builtin_amdgcn_mfma_f32_16x16x32_bf16
#define AT_LD(p)   __hip_atomic_load((p), __ATOMIC_RELAXED, __HIP_MEMORY_SCOPE_AGENT)
#define AT_ST(p,v) __hip_atomic_store((p), (v), __ATOMIC_RELAXED, __HIP_MEMORY_SCOPE_AGENT)
#define PLD(p)     (*(p))

__device__ __forceinline__ ushort f2bf(float f) {           // fp32 -> bf16 RNE
  uint u = __float_as_uint(f);
  u += 0x7fff + ((u >> 16) & 1);
  return (ushort)(u >> 16);
}
__device__ __forceinline__ float bfh(ushort h) { return __uint_as_float(((uint)h) << 16); }
__device__ __forceinline__ float ftanh(float v) {           // branch-free tanh
  float t = __expf(2.f * v);
  return 1.f - 2.f / (t + 1.f);
}
// 8 packed words (hi16|lo16) -> hi/lo short8 B-frags via v_perm (1 op/dword)
__device__ __forceinline__ void split8(const uint* w, short8& bh, short8& bl) {
  union { short8 v; uint d[4]; } H, Lo;
#pragma unroll
  for (int d = 0; d < 4; ++d) {
    H.d[d]  = __builtin_amdgcn_perm(w[2 * d + 1], w[2 * d], 0x07060302u);
    Lo.d[d] = __builtin_amdgcn_perm(w[2 * d + 1], w[2 * d], 0x05040100u);
  }
  bh = H.v; bl = Lo.v;
}

// ---------------- prep kernels ----------------

__global__ __launch_bounds__(256) void k_zero(float* __restrict__ p, int n) {
  int i = blockIdx.x * 256 + threadIdx.x;
  if (i < n) p[i] = 0.f;
}

// bias [2048] (col = g*512 + j) -> bp[j*4+g]
__global__ __launch_bounds__(256) void k_rearr_b(const float* __restrict__ src,
                                                 float* __restrict__ dst) {
  int idx = blockIdx.x * 256 + threadIdx.x;   // 2048
  int j = idx & 511, g = idx >> 9;
  dst[j * 4 + g] = src[idx];
}

// [K][2048] matrix -> A-fragment order, bf16 hi/lo split. KT=1<<ktsh k-tiles.
__global__ __launch_bounds__(256) void k_pack_A(const float* __restrict__ src,
                                                ushort* __restrict__ dst, int ktsh) {
  int idx = blockIdx.x * 256 + threadIdx.x;
  int KTm1 = (1 << ktsh) - 1;
  int j8 = idx & 7;
  int L = (idx >> 3) & 63;
  int kt = (idx >> 9) & KTm1;
  int jb = idx >> (9 + ktsh);
  int k = kt * 32 + (L >> 4) * 8 + j8;
  int m = L & 15;
  int j = jb * 4 + (m >> 2);
  int g = m & 3;
  float v = src[(size_t)k * NR + g * HH + j];
  ushort hi = f2bf(v);
  ushort lo = f2bf(v - bfh(hi));
  size_t base = ((size_t)((jb << ktsh) + kt) * 64 + L) * 16;
  dst[base + j8] = hi;
  dst[base + 8 + j8] = lo;
}

// ---------------- fused persistent 2-layer LSTM, XCD-local islands ----------
// 256 blocks x 256 thr (1/CU), ALL SYMMETRIC (R1's proven scheme: every block
// does rec + its own proj; xz lives in the MFMA accumulators, never memory).
// ISLANDS: isl = bx&7 -> one XCD (round-robin dispatch; perf-only). Island =
// 32 blocks owning cols [isl*16, isl*16+16); block jbB=bx>>3 owns units
// [jbB*16, +16); wave w owns row-tile rt=jbB*4+w (4 units) x the block's 16
// cols -> per-wave workload identical to R1 (128 B-loads, 48 MFMA, 1 ct).
// The recurrence + layer-2 proj close over the island -> sync is 32 same-XCD
// flags; islands drift independently. Proj for step G+1 runs AFTER the flag
// store of G (flag propagation hides under it - R1's mechanic).
// Phase A: h1 chain in seq (write-once -> plain cached loads, XCD-local L2).
// Phase B: h2 in 4-slot ring (atomics); each block COOPERATIVELY STAGES the
// 32 KB ring slice into LDS (pad 17) so the 4 waves share one atomic read
// pass (4x less L3 traffic). Flag protocol byte-identical to R1.
__global__ __launch_bounds__(256, 1) void k_fused(
    const float* __restrict__ x,
    const ushort* __restrict__ W1pk, const ushort* __restrict__ U1pk,
    const float* __restrict__ bp1,
    const ushort* __restrict__ W2pk, const ushort* __restrict__ U2pk,
    const float* __restrict__ bp2,
    uint* __restrict__ seq, uint* __restrict__ ring,
    int* __restrict__ hflags) {
  int tid = threadIdx.x;
  int L = tid & 63;
  int w = tid >> 6;
  int q = L >> 4, n = L & 15;
  int isl = blockIdx.x & 7;       // island == XCD (heuristic)
  int jbB = blockIdx.x >> 3;      // 0..31 within island
  int rt  = jbB * 4 + w;          // this wave's row tile (4 units)
  int j   = rt * 4 + q;           // this lane's hidden unit
  int col = isl * 16 + n;         // this lane's batch column
  int fme   = (isl * 32 + jbB) * FLS;
  int fpoll = (isl * 32 + (L & 31)) * FLS;

  __shared__ uint hstage[512 * 17];   // phase-B staged h2 slice (pad 17)

  // resident A-frags: U (16 kt, 128 VGPR) + W1 (4 kt, 32 VGPR; dead in B)
  short8 uh[16], ul[16], w1h[4], w1l[4];
#pragma unroll
  for (int kt = 0; kt < 16; ++kt) {
    const ushort* pp = U1pk + (((size_t)rt * 16 + kt) * 64 + L) * 16;
    uh[kt] = *(const short8*)pp; ul[kt] = *(const short8*)(pp + 8);
  }
#pragma unroll
  for (int kt = 0; kt < 4; ++kt) {
    const ushort* pp = W1pk + (((size_t)rt * 4 + kt) * 64 + L) * 16;
    w1h[kt] = *(const short8*)pp; w1l[kt] = *(const short8*)(pp + 8);
  }
  float4 bv = *(const float4*)(bp1 + j * 4);
  float c_reg = 0.f;
  f32x4 a0 = {0.f, 0.f, 0.f, 0.f}, a1 = a0, a2 = a0;   // xz + U*h accumulators

// xz1(T) = W1 * x(T): fp32 x split on the fly, accumulate into a0..a2
#define XPROJ(T) {                                                       \
    const float* xp = x + ((size_t)col * TT + (T)) * FF + q * 8;         \
    _Pragma("unroll")                                                    \
    for (int kt = 0; kt < 4; ++kt) {                                     \
      float4 v0 = *(const float4*)(xp + kt * 32);                        \
      float4 v1 = *(const float4*)(xp + kt * 32 + 4);                    \
      float xf[8] = {v0.x, v0.y, v0.z, v0.w, v1.x, v1.y, v1.z, v1.w};    \
      short8 xh, xl;                                                     \
      _Pragma("unroll")                                                  \
      for (int u = 0; u < 8; ++u) {                                      \
        ushort hi = f2bf(xf[u]);                                         \
        xl[u] = (short)f2bf(xf[u] - bfh(hi));                            \
        xh[u] = (short)hi;                                               \
      }                                                                  \
      a0 = MFMA(w1h[kt], xh, a0, 0, 0, 0);                               \
      a1 = MFMA(w1l[kt], xh, a1, 0, 0, 0);                               \
      a2 = MFMA(w1h[kt], xl, a2, 0, 0, 0);                               \
    } }

// xz2(SP) = W2 * h1(SP): seq plain loads (island-local, L2-hot), W2 streamed
#define G1PROJ(SP) {                                                     \
    const uint* hc = seq + (size_t)(SP) * HB + (size_t)(q * 8) * BB + col; \
    uint wv[16][8];                                                      \
    _Pragma("unroll")                                                    \
    for (int kt = 0; kt < 16; ++kt)                                      \
      _Pragma("unroll")                                                  \
      for (int u = 0; u < 8; ++u)                                        \
        wv[kt][u] = PLD(hc + (size_t)(kt * 32 + u) * BB);                \
    _Pragma("unroll")                                                    \
    for (int kt = 0; kt < 16; ++kt) {                                    \
      short8 bh, bl;                                                     \
      split8(wv[kt], bh, bl);                                            \
      const ushort* ab = W2pk + (((size_t)rt * 16 + kt) * 64 + L) * 16;  \
      short8 ah = *(const short8*)ab, al = *(const short8*)(ab + 8);     \
      a0 = MFMA(ah, bh, a0, 0, 0, 0);                                    \
      a1 = MFMA(al, bh, a1, 0, 0, 0);                                    \
      a2 = MFMA(ah, bl, a2, 0, 0, 0);                                    \
    } }

  XPROJ(0)   // xz(0) into accumulators before the chain starts

#pragma unroll 1
  for (int G = 0; G < 2 * TT; ++G) {
    if (G == TT) {                // layer 2: swap U frags + bias; c carries
#pragma unroll
      for (int kt = 0; kt < 16; ++kt) {
        const ushort* pp = U2pk + (((size_t)rt * 16 + kt) * 64 + L) * 16;
        uh[kt] = *(const short8*)pp; ul[kt] = *(const short8*)(pp + 8);
      }
      bv = *(const float4*)(bp2 + j * 4);
    }
    // island poll: 32 same-XCD producers at >= G (flag = data drained)
    while (true) {
      int hf = AT_LD(hflags + fpoll);
      if (__all(hf >= G)) break;
    }
    asm volatile("" ::: "memory");

    if (G != 0) {
      if (G < TT) {               // phase A: seq write-once -> plain loads
        const uint* hc = seq + (size_t)(G - 1) * HB + (size_t)(q * 8) * BB + col;
        uint wv[16][8];
#pragma unroll
        for (int kt = 0; kt < 16; ++kt)
#pragma unroll
          for (int u = 0; u < 8; ++u)
            wv[kt][u] = PLD(hc + (size_t)(kt * 32 + u) * BB);
#pragma unroll
        for (int kt = 0; kt < 16; ++kt) {
          short8 bh, bl;
          split8(wv[kt], bh, bl);
          a0 = MFMA(uh[kt], bh, a0, 0, 0, 0);
          a1 = MFMA(ul[kt], bh, a1, 0, 0, 0);
          a2 = MFMA(uh[kt], bl, a2, 0, 0, 0);
        }
      } else {                    // phase B: cooperative LDS stage of ring
        {
          const uint* rb = ring + (size_t)((G - 1) & 3) * HB + isl * 16;
#pragma unroll
          for (int i = 0; i < 32; ++i) {
            int word = i * 256 + tid;          // coalesced: 16 lanes per line
            int k = word >> 4, c = word & 15;
            hstage[k * 17 + c] = AT_LD(rb + (size_t)k * BB + c);
          }
        }
        __syncthreads();          // stage complete (prior reads done pre-flag)
#pragma unroll
        for (int kt = 0; kt < 16; ++kt) {
          uint wv8[8];
#pragma unroll
          for (int u = 0; u < 8; ++u)
            wv8[u] = hstage[(kt * 32 + q * 8 + u) * 17 + n];
          short8 bh, bl;
          split8(wv8, bh, bl);
          a0 = MFMA(uh[kt], bh, a0, 0, 0, 0);
          a1 = MFMA(ul[kt], bh, a1, 0, 0, 0);
          a2 = MFMA(uh[kt], bl, a2, 0, 0, 0);
        }
      }
    }
    // activations (accumulators already hold U*h + W*x; add bias here)
    float z0 = a0.x + a1.x + a2.x + bv.x;
    float z1 = a0.y + a1.y + a2.y + bv.y;
    float z2 = a0.z + a1.z + a2.z + bv.z;
    float z3 = a0.w + a1.w + a2.w + bv.w;
    float ig = 1.f / (1.f + __expf(-z0));
    float fg = 1.f / (1.f + __expf(-z1));
    float gg = ftanh(z2);
    float og = 1.f / (1.f + __expf(-z3));
    c_reg = fg * c_reg + ig * gg;
    float hn = og * ftanh(c_reg);
    ushort hh = f2bf(hn);
    uint wd = (((uint)hh) << 16) | (uint)f2bf(hn - bfh(hh));

    if (G < TT) {
      AT_ST(&seq[(size_t)G * HB + (size_t)j * BB + col], wd);
      if (G == TT - 1)            // seed h2(-1) into ring slot 3
        AT_ST(&ring[(size_t)3 * HB + (size_t)j * BB + col], wd);
    } else {
      AT_ST(&ring[(size_t)(G & 3) * HB + (size_t)j * BB + col], wd);
    }
    __syncthreads();              // drain all 4 waves' stores before the flag
    if (tid == 0) AT_ST(hflags + fme, G + 1);

    // next step's projection in the flag-propagation shadow
    if (G + 1 < 2 * TT) {
      a0 = (f32x4){0.f, 0.f, 0.f, 0.f}; a1 = a0; a2 = a0;
      if (G + 1 < TT) { XPROJ(G + 1) }
      else            { G1PROJ(G + 1 - TT) }
    }
  }
}

// ---------------- dense + softmax (reads ring slot 3 words) ----------------
__global__ __launch_bounds__(64) void k_dense(const uint* __restrict__ h2,
                                              const float* __restrict__ Wd,
                                              const float* __restrict__ bd,
                                              float* __restrict__ out) {
  int b = blockIdx.x * 64 + threadIdx.x;
  float acc[10];
#pragma unroll
  for (int c = 0; c < 10; ++c) acc[c] = bd[c];
  for (int k = 0; k < HH; ++k) {
    uint w = h2[k * BB + b];
    float hv = __uint_as_float(w & 0xffff0000u) + __uint_as_float(w << 16);
#pragma unroll
    for (int c = 0; c < 10; ++c) acc[c] = fmaf(hv, Wd[k * 10 + c], acc[c]);
  }
  float m = acc[0];
#pragma unroll
  for (int c = 1; c < 10; ++c) m = fmaxf(m, acc[c]);
  float s = 0.f;
#pragma unroll
  for (int c = 0; c < 10; ++c) { acc[c] = __expf(acc[c] - m); s += acc[c]; }
  float inv = 1.f / s;
#pragma unroll
  for (int c = 0; c < 10; ++c) out[b * 10 + c] = acc[c] * inv;
}

// ---------------- host ----------------
extern "C" void kernel_launch(void* const* d_in, const int* in_sizes, int n_in,
                              void* d_out, int out_size, void* d_ws, size_t ws_size,
                              hipStream_t stream) {
  const float* x  = (const float*)d_in[0];
  const float* W1 = (const float*)d_in[1];
  const float* U1 = (const float*)d_in[2];
  const float* b1 = (const float*)d_in[3];
  const float* W2 = (const float*)d_in[4];
  const float* U2 = (const float*)d_in[5];
  const float* b2 = (const float*)d_in[6];
  const float* Wd = (const float*)d_in[7];
  const float* bd = (const float*)d_in[8];
  float* out = (float*)d_out;

  // workspace layout (~143 MB, < proven 181 MB)
  uint*   seq   = (uint*)d_ws;                      // [512][HB]   128 MB
  uint*   ring  = seq + (size_t)TT * HB;            // [4][HB]       1 MB
  ushort* W1pk  = (ushort*)(ring + (size_t)4 * HB); //   524,288 ush
  ushort* U1pk  = W1pk + (size_t)524288;            // 2,097,152 ush
  ushort* U2pk  = U1pk + (size_t)2097152;           // 2,097,152 ush
  ushort* W2pk  = U2pk + (size_t)2097152;           // 2,097,152 ush
  float*  bp1   = (float*)(W2pk + (size_t)2097152); // 2,048 f
  float*  bp2   = bp1 + NR;                         // 2,048 f
  int*    hflags = (int*)(bp2 + NR);                // 256*FLS ints

  k_zero<<<16, 256, 0, stream>>>((float*)hflags, 256 * FLS);
  k_rearr_b<<<8, 256, 0, stream>>>(b1, bp1);
  k_rearr_b<<<8, 256, 0, stream>>>(b2, bp2);
  k_pack_A<<<1024, 256, 0, stream>>>(W1, W1pk, 2);   // K=128 -> 4 k-tiles
  k_pack_A<<<4096, 256, 0, stream>>>(U1, U1pk, 4);   // K=512 -> 16 k-tiles
  k_pack_A<<<4096, 256, 0, stream>>>(U2, U2pk, 4);
  k_pack_A<<<4096, 256, 0, stream>>>(W2, W2pk, 4);

  k_fused<<<256, 256, 0, stream>>>(x, W1pk, U1pk, bp1, W2pk, U2pk, bp2,
                                   seq, ring, hflags);
  k_dense<<<2, 64, 0, stream>>>(ring + (size_t)3 * HB, Wd, bd, out);
}